// Round 7
// baseline (117.795 us; speedup 1.0000x reference)
//
#include <hip/hip_runtime.h>
#include <cstdint>
#include <cstddef>

#define NPTS 8192
#define NWORDS 128          // NPTS/64
#define XCOLS 10            // 3 coords + batch + feat + 5 seg
#define MIN_PTS 5
#define NGROUPS 10
#define BIGC 0x3fffffff

#define NLCAP 1536          // max nodes per group (expect ~820)
#define NSLICE 24           // row slices per group (rows r == s mod 24)
#define ECAP_S 2048         // per-slice edge region cap (expect ~225/slice)
#define PT 1024             // k_pairs threads (16 waves)
#define PWV 16
#define GT 1024             // k_graph threads (16 waves)
#define GWV 16

// ---------------- pairs: membership + row-slice adjacency --------------------
// Block (g,s): rebuilds group g's ordered node list from x (ballot+prefix),
// fills pts in LDS (w = 0.5|p|^2 - EPS2/4; test: dot > wu+wv), computes rows
// r == s (mod 24), one row per lane; 16 waves partition the 32-col chunks.
// Outputs (ALL plain stores, nothing pre-zeroed):
//   eAll[(g*24+s)*ECAP_S + .]  packed edges u<v        ecnt[g*24+s] count
//   corebm_g[g*24+s]           ballot: bit l = core(row s+24l)
//   nlist_g / nn_g             from slice 0 only
__global__ void __launch_bounds__(PT) k_pairs(
        const float* __restrict__ x, unsigned int* __restrict__ eAll,
        int* __restrict__ ecnt, unsigned long long* __restrict__ corebm_g,
        int* __restrict__ nlist_g, int* __restrict__ nn_g) {
    __shared__ float4 pts[NLCAP];                    // 24 KB
    __shared__ unsigned long long masks[NWORDS];     // 1 KB
    __shared__ int pref[NWORDS];                     // 0.5 KB
    __shared__ int srowdeg[64];
    __shared__ int scnt, nnS;

    const int g = blockIdx.x / NSLICE;
    const int s = blockIdx.x % NSLICE;
    const int tid = threadIdx.x, lane = tid & 63, wv = tid >> 6;

    for (int k = tid; k < NLCAP; k += PT)
        pts[k] = make_float4(0.f, 0.f, 0.f, 1.0e38f);     // sentinel: never matches
    if (tid < 64) srowdeg[tid] = 0;
    if (tid == 0) scnt = 0;

    for (int w = wv; w < NWORDS; w += PWV) {
        int i = w * 64 + lane;
        const float2* r2 = (const float2*)(x + (size_t)i * XCOLS);  // rows 40 B, 8-aligned
        float2 c23 = r2[1];                 // z, batch
        float2 c45 = r2[2];                 // feat, s0
        float2 c67 = r2[3];                 // s1, s2
        float2 c89 = r2[4];                 // s3, s4
        float best = c45.y; int bc = 0;
        if (c67.x > best) { best = c67.x; bc = 1; }
        if (c67.y > best) { best = c67.y; bc = 2; }
        if (c89.x > best) { best = c89.x; bc = 3; }
        if (c89.y > best) { best = c89.y; bc = 4; }
        unsigned long long bm = __ballot((int)c23.y * 5 + bc == g);
        if (lane == 0) masks[w] = bm;
    }
    __syncthreads();
    if (wv == 0) {                          // 2-chunk scan of 128 popcounts
        int v0 = __popcll(masks[lane]);
        int incl = v0;
        #pragma unroll
        for (int st = 1; st < 64; st <<= 1) {
            int o = __shfl_up(incl, st);
            if (lane >= st) incl += o;
        }
        pref[lane] = incl - v0;
        int tot0 = __shfl(incl, 63);
        int v1 = __popcll(masks[64 + lane]);
        int incl1 = v1;
        #pragma unroll
        for (int st = 1; st < 64; st <<= 1) {
            int o = __shfl_up(incl1, st);
            if (lane >= st) incl1 += o;
        }
        pref[64 + lane] = tot0 + incl1 - v1;
        if (lane == 63) nnS = tot0 + incl1;
    }
    __syncthreads();
    for (int w = wv; w < NWORDS; w += PWV) {
        unsigned long long bm = masks[w];
        if ((bm >> lane) & 1ull) {
            int p = pref[w] + __popcll(bm & ((1ull << lane) - 1ull));
            if (p < NLCAP) {
                int i = w * 64 + lane;
                const float2* r2 = (const float2*)(x + (size_t)i * XCOLS);
                float2 c01 = r2[0]; float2 c23 = r2[1];
                float px = c01.x, py = c01.y, pz = c23.x;
                // d2<EPS2  <=>  dot(u,v) > wu+wv  with w = 0.5|p|^2 - EPS2/4
                pts[p] = make_float4(px, py, pz,
                                     0.5f * (px*px + py*py + pz*pz) - 56.25f);
                if (s == 0) nlist_g[g * NLCAP + p] = i;
            }
        }
    }
    if (s == 0 && tid == 0) nn_g[g] = (nnS > NLCAP) ? NLCAP : nnS;
    __syncthreads();
    const int NN = (nnS > NLCAP) ? NLCAP : nnS;

    const int rrow = s + NSLICE * lane;               // covers 0..1535 exactly
    const float4 qu = pts[rrow];
    int rdeg = 0;
    const int NC = (NN + 31) >> 5;
    unsigned int* eg = eAll + (size_t)(g * NSLICE + s) * ECAP_S;
    for (int c = wv; c < NC; c += PWV) {
        int base = c << 5;
        unsigned int bits = 0u;
        #pragma unroll
        for (int t = 0; t < 32; t++) {
            float4 qv = pts[base + t];                // wave-uniform broadcast
            float dt = qu.x*qv.x + qu.y*qv.y + qu.z*qv.z;
            bits |= (dt > qu.w + qv.w) ? (1u << t) : 0u;
        }
        rdeg += __popc(bits);                          // full row degree (incl self)
        int d = rrow - base;                           // keep only v > u for edges
        if (d >= 31) bits = 0u;
        else if (d >= 0) bits &= ~((2u << d) - 1u);
        int cnt = __popc(bits);
        int incl = cnt;
        #pragma unroll
        for (int st = 1; st < 64; st <<= 1) {
            int o = __shfl_up(incl, st);
            if (lane >= st) incl += o;
        }
        int tot = __shfl(incl, 63);
        if (tot > 0) {
            int rb = 0;
            if (lane == 63) rb = atomicAdd(&scnt, tot);
            rb = __shfl(rb, 63);
            unsigned int p = (unsigned int)(rb + incl - cnt);
            unsigned int b = bits;
            unsigned int uhi = (unsigned int)rrow << 11;
            while (b) {
                int t = __ffs(b) - 1; b &= b - 1;
                if (p < ECAP_S) eg[p] = uhi | (unsigned int)(base + t);
                p++;
            }
        }
    }
    if (rdeg > 0) atomicAdd(&srowdeg[lane], rdeg);    // sum across the 16 waves
    __syncthreads();
    if (wv == 0) {
        // bit l of corebm = core status of row s + 24*l (this block owns them)
        unsigned long long cb = __ballot(srowdeg[lane] >= MIN_PTS);
        if (lane == 0) {
            corebm_g[g * NSLICE + s] = cb;
            ecnt[g * NSLICE + s] = (scnt > ECAP_S) ? ECAP_S : scnt;
        }
    }
}

// ---------------- graph: single-pass union-find -> rank -> border -> output --
// 10 blocks. Edges read straight from global (L2-hot, ~22 KB/group) twice:
// once for union (core-core), once for border (core-noncore). No staging, no
// SV rounds: lock-free min-hook union-find (hooks always larger->smaller root
// via atomicCAS, so the forest is acyclic, never severed, and the final root
// of each component is its minimum core index = reference rep semantics).
__global__ void __launch_bounds__(GT) k_graph(
        const unsigned int* __restrict__ eAll, const int* __restrict__ ecnt,
        const unsigned long long* __restrict__ corebm_g,
        const int* __restrict__ nlist_g, const int* __restrict__ nn_g,
        const float* __restrict__ x, float* __restrict__ out) {
    __shared__ int spar[NLCAP];                      // 6 KB  union-find parent
    __shared__ int scid[NLCAP];                      // 6 KB  rep -> cluster id
    __shared__ int scid2[NLCAP];                     // 6 KB  node -> cluster id
    __shared__ int sbmin[NLCAP];                     // 6 KB  border min cid
    __shared__ int nlist[NLCAP];                     // 6 KB
    __shared__ unsigned long long cbm[NSLICE];       // (s,l) layout from pairs
    __shared__ unsigned long long corelin[NLCAP/64]; // linear-index layout
    __shared__ unsigned long long repbm[NLCAP/64];
    __shared__ int pref24[NLCAP/64];
    __shared__ int cnts[NSLICE];

    const int g = blockIdx.x;
    const int tid = threadIdx.x, lane = tid & 63, wv = tid >> 6;
    const int NN = nn_g[g];
    volatile int* vpar = spar;

    if (wv == 0 && lane < NSLICE) {
        int c = ecnt[g * NSLICE + lane];
        cnts[lane] = (c > ECAP_S) ? ECAP_S : c;
        cbm[lane] = corebm_g[g * NSLICE + lane];
    }
    for (int k = tid; k < NLCAP; k += GT) {
        spar[k] = k;
        sbmin[k] = BIGC;
        nlist[k] = nlist_g[g * NLCAP + k];
    }
    __syncthreads();
    for (int w = wv; w < NLCAP / 64; w += GWV) {     // (s,l) -> linear bitmap
        int l = w * 64 + lane;
        bool b = (cbm[l % NSLICE] >> (l / NSLICE)) & 1ull;
        unsigned long long bm = __ballot(b);
        if (lane == 0) corelin[w] = bm;
    }
    __syncthreads();
    auto corebit = [&](int l) -> bool { return (corelin[l >> 6] >> (l & 63)) & 1ull; };

    // ---- union pass: one sweep over all edges, core-core only
    for (int s2 = 0; s2 < NSLICE; s2++) {
        int cn = cnts[s2];
        const unsigned int* eg = eAll + (size_t)(g * NSLICE + s2) * ECAP_S;
        for (int e = tid; e < cn; e += GT) {
            unsigned int pk = eg[e];
            int u = (int)(pk >> 11), v = (int)(pk & 2047u);
            if (!(corebit(u) && corebit(v))) continue;
            int ru = u;
            while (true) { int p = vpar[ru]; if (p == ru) break; ru = p; }
            int rv = v;
            while (true) { int p = vpar[rv]; if (p == rv) break; rv = p; }
            while (ru != rv) {
                if (ru > rv) { int t = ru; ru = rv; rv = t; }    // ru < rv
                int old = atomicCAS(&spar[rv], rv, ru);
                if (old == rv) break;                 // hooked rv under ru
                rv = old;                             // rv was re-rooted; follow
                while (true) { int p = vpar[rv]; if (p == rv) break; rv = p; }
            }
        }
    }
    __syncthreads();
    // ---- full compression: spar[k] = component root (min core index)
    for (int k = tid; k < NN; k += GT) {
        int p = spar[k];
        while (true) { int q = vpar[p]; if (q == p) break; p = q; }
        spar[k] = p;
    }
    __syncthreads();
    // ---- reps bitmap + parallel rank over 24 words
    for (int w = wv; w < NLCAP / 64; w += GWV) {
        int l = w * 64 + lane;
        bool isr = (l < NN) && corebit(l) && (spar[l] == l);
        unsigned long long bm = __ballot(isr);
        if (lane == 0) repbm[w] = bm;
    }
    __syncthreads();
    if (wv == 0 && lane < NLCAP / 64) {
        int c = __popcll(repbm[lane]);
        int incl = c;
        #pragma unroll
        for (int st = 1; st < 32; st <<= 1) {
            int o = __shfl_up(incl, st);
            if (lane >= st) incl += o;
        }
        pref24[lane] = incl - c;
    }
    __syncthreads();
    for (int w = wv; w < NLCAP / 64; w += GWV) {
        int l = w * 64 + lane;
        unsigned long long bm = repbm[w];
        if ((bm >> lane) & 1ull)
            scid[l] = pref24[w] + __popcll(bm & ((1ull << lane) - 1ull));
    }
    __syncthreads();
    // ---- node -> cluster id (separate array: no RAW hazard, no extra barrier)
    for (int k = tid; k < NLCAP; k += GT)
        scid2[k] = (k < NN && corebit(k)) ? scid[spar[k]] : BIGC;
    __syncthreads();
    // ---- border pass: second edge sweep, core-noncore only
    for (int s2 = 0; s2 < NSLICE; s2++) {
        int cn = cnts[s2];
        const unsigned int* eg = eAll + (size_t)(g * NSLICE + s2) * ECAP_S;
        for (int e = tid; e < cn; e += GT) {
            unsigned int pk = eg[e];
            int u = (int)(pk >> 11), v = (int)(pk & 2047u);
            bool cu = corebit(u), cv = corebit(v);
            if (cu == cv) continue;
            if (cu) atomicMin(&sbmin[v], scid2[u]);
            else    atomicMin(&sbmin[u], scid2[v]);
        }
    }
    __syncthreads();
    // ---- final labels + clustered output (groups cover disjoint point sets)
    for (int k = tid; k < NN; k += GT) {
        int i = nlist[k];
        int c = scid2[k];
        int lbl = (c != BIGC) ? c : ((sbmin[k] < BIGC) ? sbmin[k] : -1);
        out[i] = (float)lbl;
        const float* r = x + (size_t)i * XCOLS;
        float* o = out + NPTS + (size_t)i * 5;
        bool keep = lbl >= 0;
        #pragma unroll
        for (int c5 = 0; c5 < 5; c5++) o[c5] = keep ? r[c5] : 0.0f;
    }
}

extern "C" void kernel_launch(void* const* d_in, const int* in_sizes, int n_in,
                              void* d_out, int out_size, void* d_ws, size_t ws_size,
                              hipStream_t stream) {
    const float* x = (const float*)d_in[0];
    float* out = (float*)d_out;
    char* ws = (char*)d_ws;

    // workspace (~2.03 MB); NOTHING needs pre-zeroing (plain-stored counts/masks)
    unsigned int* eAll       = (unsigned int*)(ws);                 // 240*2048*4 = 1966080
    int* ecnt                = (int*)(ws + 1966080);                // 240*4 (pad 1024)
    unsigned long long* cbm  = (unsigned long long*)(ws + 1967104); // 240*8 = 1920
    int* nlist_g             = (int*)(ws + 1969024);                // 61440
    int* nn_g                = (int*)(ws + 2030464);                // 64

    k_pairs<<<NGROUPS * NSLICE, PT, 0, stream>>>(x, eAll, ecnt, cbm, nlist_g, nn_g);
    k_graph<<<NGROUPS, GT, 0, stream>>>(eAll, ecnt, cbm, nlist_g, nn_g, x, out);
}

// Round 8
// 80.995 us; speedup vs baseline: 1.4543x; 1.4543x over previous
//
#include <hip/hip_runtime.h>
#include <cstdint>
#include <cstddef>

#define NPTS 8192
#define NWORDS 128          // NPTS/64
#define XCOLS 10            // 3 coords + batch + feat + 5 seg
#define MIN_PTS 5
#define NGROUPS 10
#define BIGC 0x3fffffff

#define NLCAP 1536          // max nodes per group (expect ~820)
#define NSLICE 24           // row slices per group (rows r == s mod 24)
#define ECAP_S 2048         // per-slice edge region cap (expect ~225/slice)
#define EACAP 8192          // flat staged edges per group (expect ~5.4k)
#define PT 1024             // k_pairs threads (16 waves)
#define PWV 16
#define GT 1024             // k_graph threads (16 waves)
#define GWV 16

// ---------------- pairs: membership + row-slice adjacency --------------------
// Block (g,s): rebuilds group g's ordered node list from x (ballot+prefix),
// fills pts in LDS (w = 0.5|p|^2 - EPS2/4; test: dot > wu+wv), computes rows
// r == s (mod 24), one row per lane; 16 waves partition the 32-col chunks.
// Outputs (ALL plain stores, nothing pre-zeroed):
//   eAll[(g*24+s)*ECAP_S + .]  packed edges u<v        ecnt[g*24+s] count
//   corebm_g[g*24+s]           ballot: bit l = core(row s+24l)
//   nlist_g / nn_g             from slice 0 only
__global__ void __launch_bounds__(PT) k_pairs(
        const float* __restrict__ x, unsigned int* __restrict__ eAll,
        int* __restrict__ ecnt, unsigned long long* __restrict__ corebm_g,
        int* __restrict__ nlist_g, int* __restrict__ nn_g) {
    __shared__ float4 pts[NLCAP];                    // 24 KB
    __shared__ unsigned long long masks[NWORDS];     // 1 KB
    __shared__ int pref[NWORDS];                     // 0.5 KB
    __shared__ int srowdeg[64];
    __shared__ int scnt, nnS;

    const int g = blockIdx.x / NSLICE;
    const int s = blockIdx.x % NSLICE;
    const int tid = threadIdx.x, lane = tid & 63, wv = tid >> 6;

    for (int k = tid; k < NLCAP; k += PT)
        pts[k] = make_float4(0.f, 0.f, 0.f, 1.0e38f);     // sentinel: never matches
    if (tid < 64) srowdeg[tid] = 0;
    if (tid == 0) scnt = 0;

    for (int w = wv; w < NWORDS; w += PWV) {
        int i = w * 64 + lane;
        const float2* r2 = (const float2*)(x + (size_t)i * XCOLS);  // rows 40 B, 8-aligned
        float2 c23 = r2[1];                 // z, batch
        float2 c45 = r2[2];                 // feat, s0
        float2 c67 = r2[3];                 // s1, s2
        float2 c89 = r2[4];                 // s3, s4
        float best = c45.y; int bc = 0;
        if (c67.x > best) { best = c67.x; bc = 1; }
        if (c67.y > best) { best = c67.y; bc = 2; }
        if (c89.x > best) { best = c89.x; bc = 3; }
        if (c89.y > best) { best = c89.y; bc = 4; }
        unsigned long long bm = __ballot((int)c23.y * 5 + bc == g);
        if (lane == 0) masks[w] = bm;
    }
    __syncthreads();
    if (wv == 0) {                          // 2-chunk scan of 128 popcounts
        int v0 = __popcll(masks[lane]);
        int incl = v0;
        #pragma unroll
        for (int st = 1; st < 64; st <<= 1) {
            int o = __shfl_up(incl, st);
            if (lane >= st) incl += o;
        }
        pref[lane] = incl - v0;
        int tot0 = __shfl(incl, 63);
        int v1 = __popcll(masks[64 + lane]);
        int incl1 = v1;
        #pragma unroll
        for (int st = 1; st < 64; st <<= 1) {
            int o = __shfl_up(incl1, st);
            if (lane >= st) incl1 += o;
        }
        pref[64 + lane] = tot0 + incl1 - v1;
        if (lane == 63) nnS = tot0 + incl1;
    }
    __syncthreads();
    for (int w = wv; w < NWORDS; w += PWV) {
        unsigned long long bm = masks[w];
        if ((bm >> lane) & 1ull) {
            int p = pref[w] + __popcll(bm & ((1ull << lane) - 1ull));
            if (p < NLCAP) {
                int i = w * 64 + lane;
                const float2* r2 = (const float2*)(x + (size_t)i * XCOLS);
                float2 c01 = r2[0]; float2 c23 = r2[1];
                float px = c01.x, py = c01.y, pz = c23.x;
                // d2<EPS2  <=>  dot(u,v) > wu+wv  with w = 0.5|p|^2 - EPS2/4
                pts[p] = make_float4(px, py, pz,
                                     0.5f * (px*px + py*py + pz*pz) - 56.25f);
                if (s == 0) nlist_g[g * NLCAP + p] = i;
            }
        }
    }
    if (s == 0 && tid == 0) nn_g[g] = (nnS > NLCAP) ? NLCAP : nnS;
    __syncthreads();
    const int NN = (nnS > NLCAP) ? NLCAP : nnS;

    const int rrow = s + NSLICE * lane;               // covers 0..1535 exactly
    const float4 qu = pts[rrow];
    int rdeg = 0;
    const int NC = (NN + 31) >> 5;
    unsigned int* eg = eAll + (size_t)(g * NSLICE + s) * ECAP_S;
    for (int c = wv; c < NC; c += PWV) {
        int base = c << 5;
        unsigned int bits = 0u;
        #pragma unroll
        for (int t = 0; t < 32; t++) {
            float4 qv = pts[base + t];                // wave-uniform broadcast
            float dt = qu.x*qv.x + qu.y*qv.y + qu.z*qv.z;
            bits |= (dt > qu.w + qv.w) ? (1u << t) : 0u;
        }
        rdeg += __popc(bits);                          // full row degree (incl self)
        int d = rrow - base;                           // keep only v > u for edges
        if (d >= 31) bits = 0u;
        else if (d >= 0) bits &= ~((2u << d) - 1u);
        int cnt = __popc(bits);
        int incl = cnt;
        #pragma unroll
        for (int st = 1; st < 64; st <<= 1) {
            int o = __shfl_up(incl, st);
            if (lane >= st) incl += o;
        }
        int tot = __shfl(incl, 63);
        if (tot > 0) {
            int rb = 0;
            if (lane == 63) rb = atomicAdd(&scnt, tot);
            rb = __shfl(rb, 63);
            unsigned int p = (unsigned int)(rb + incl - cnt);
            unsigned int b = bits;
            unsigned int uhi = (unsigned int)rrow << 11;
            while (b) {
                int t = __ffs(b) - 1; b &= b - 1;
                if (p < ECAP_S) eg[p] = uhi | (unsigned int)(base + t);
                p++;
            }
        }
    }
    if (rdeg > 0) atomicAdd(&srowdeg[lane], rdeg);    // sum across the 16 waves
    __syncthreads();
    if (wv == 0) {
        // bit l of corebm = core status of row s + 24*l (this block owns them)
        unsigned long long cb = __ballot(srowdeg[lane] >= MIN_PTS);
        if (lane == 0) {
            corebm_g[g * NSLICE + s] = cb;
            ecnt[g * NSLICE + s] = (scnt > ECAP_S) ? ECAP_S : scnt;
        }
    }
}

// ---------------- graph: stage -> ECL union-find -> rank -> border -> output -
// 10 blocks. Edges staged ONCE into flat LDS in parallel (waves partition
// slices, lanes coalesce); union-find is ECL-CC: path-halving representative
// + CAS hook larger->smaller root (root = min core index = reference rep).
__global__ void __launch_bounds__(GT) k_graph(
        const unsigned int* __restrict__ eAll, const int* __restrict__ ecnt,
        const unsigned long long* __restrict__ corebm_g,
        const int* __restrict__ nlist_g, const int* __restrict__ nn_g,
        const float* __restrict__ x, float* __restrict__ out) {
    __shared__ unsigned int eA[EACAP];               // 32 KB flat staged edges
    __shared__ int spar[NLCAP];                      // 6 KB  union-find parent
    __shared__ int scid[NLCAP];                      // 6 KB  rep -> cluster id
    __shared__ int scid2[NLCAP];                     // 6 KB  node -> cluster id
    __shared__ int sbmin[NLCAP];                     // 6 KB  border min cid
    __shared__ int nlist[NLCAP];                     // 6 KB
    __shared__ unsigned long long cbm[NSLICE];       // (s,l) layout from pairs
    __shared__ unsigned long long corelin[NLCAP/64]; // linear-index layout
    __shared__ unsigned long long repbm[NLCAP/64];
    __shared__ int pref24[NLCAP/64];
    __shared__ int offs[NSLICE], cnts[NSLICE];
    __shared__ int NAs;

    const int g = blockIdx.x;
    const int tid = threadIdx.x, lane = tid & 63, wv = tid >> 6;
    const int NN = nn_g[g];
    volatile int* vpar = spar;

    if (wv == 0) {                                   // counts -> prefix, masks
        int c = 0;
        if (lane < NSLICE) {
            c = ecnt[g * NSLICE + lane];
            c = (c > ECAP_S) ? ECAP_S : c;
            cbm[lane] = corebm_g[g * NSLICE + lane];
        }
        int incl = c;
        #pragma unroll
        for (int st = 1; st < 32; st <<= 1) {
            int o = __shfl_up(incl, st);
            if (lane >= st) incl += o;
        }
        if (lane < NSLICE) { offs[lane] = incl - c; cnts[lane] = c; }
        if (lane == NSLICE - 1) NAs = incl;
    }
    for (int k = tid; k < NLCAP; k += GT) {
        spar[k] = k;
        sbmin[k] = BIGC;
        nlist[k] = nlist_g[g * NLCAP + k];
    }
    __syncthreads();
    const int NA = (NAs > EACAP) ? EACAP : NAs;
    // parallel stage: waves partition slices; lanes coalesce within a slice
    for (int s2 = wv; s2 < NSLICE; s2 += GWV) {
        const unsigned int* eg = eAll + (size_t)(g * NSLICE + s2) * ECAP_S;
        int off = offs[s2], cn = cnts[s2];
        for (int o = lane; o < cn; o += 64) {
            int dst = off + o;
            if (dst < EACAP) eA[dst] = eg[o];
        }
    }
    for (int w = wv; w < NLCAP / 64; w += GWV) {     // (s,l) -> linear bitmap
        int l = w * 64 + lane;
        bool b = (cbm[l % NSLICE] >> (l / NSLICE)) & 1ull;
        unsigned long long bm = __ballot(b);
        if (lane == 0) corelin[w] = bm;
    }
    __syncthreads();
    auto corebit = [&](int l) -> bool { return (corelin[l >> 6] >> (l & 63)) & 1ull; };
    // ECL-CC representative: walk down (parents strictly decrease), halving
    auto findrep = [&](int v) -> int {
        int curr = vpar[v];
        if (curr != v) {
            int prev = v, next;
            while (curr > (next = vpar[curr])) {
                vpar[prev] = next;                    // shortcut to grandparent
                prev = curr;
                curr = next;
            }
        }
        return curr;
    };

    // ---- union pass: one parallel sweep over flat eA, core-core only
    for (int e = tid; e < NA; e += GT) {
        unsigned int pk = eA[e];
        int u = (int)(pk >> 11), v = (int)(pk & 2047u);
        if (!(corebit(u) && corebit(v))) continue;
        int ru = findrep(u), rv = findrep(v);
        bool repeat;
        do {
            repeat = false;
            if (ru != rv) {
                int lo = (ru < rv) ? ru : rv;
                int hi = (ru < rv) ? rv : ru;
                int ret = atomicCAS(&spar[hi], hi, lo);
                if (ret != hi && ret != lo) { ru = ret; rv = lo; repeat = true; }
            }
        } while (repeat);
    }
    __syncthreads();
    // ---- full compression: spar[k] = component root (min core index)
    for (int k = tid; k < NN; k += GT)
        spar[k] = findrep(k);
    __syncthreads();
    // ---- reps bitmap + parallel rank over 24 words
    for (int w = wv; w < NLCAP / 64; w += GWV) {
        int l = w * 64 + lane;
        bool isr = (l < NN) && corebit(l) && (spar[l] == l);
        unsigned long long bm = __ballot(isr);
        if (lane == 0) repbm[w] = bm;
    }
    __syncthreads();
    if (wv == 0 && lane < NLCAP / 64) {
        int c = __popcll(repbm[lane]);
        int incl = c;
        #pragma unroll
        for (int st = 1; st < 32; st <<= 1) {
            int o = __shfl_up(incl, st);
            if (lane >= st) incl += o;
        }
        pref24[lane] = incl - c;
    }
    __syncthreads();
    for (int w = wv; w < NLCAP / 64; w += GWV) {
        int l = w * 64 + lane;
        unsigned long long bm = repbm[w];
        if ((bm >> lane) & 1ull)
            scid[l] = pref24[w] + __popcll(bm & ((1ull << lane) - 1ull));
    }
    __syncthreads();
    // ---- node -> cluster id (separate array: no RAW hazard)
    for (int k = tid; k < NLCAP; k += GT)
        scid2[k] = (k < NN && corebit(k)) ? scid[spar[k]] : BIGC;
    __syncthreads();
    // ---- border pass over staged LDS edges, core-noncore only
    for (int e = tid; e < NA; e += GT) {
        unsigned int pk = eA[e];
        int u = (int)(pk >> 11), v = (int)(pk & 2047u);
        bool cu = corebit(u), cv = corebit(v);
        if (cu == cv) continue;
        if (cu) atomicMin(&sbmin[v], scid2[u]);
        else    atomicMin(&sbmin[u], scid2[v]);
    }
    __syncthreads();
    // ---- final labels + clustered output (groups cover disjoint point sets)
    for (int k = tid; k < NN; k += GT) {
        int i = nlist[k];
        int c = scid2[k];
        int lbl = (c != BIGC) ? c : ((sbmin[k] < BIGC) ? sbmin[k] : -1);
        out[i] = (float)lbl;
        const float* r = x + (size_t)i * XCOLS;
        float* o = out + NPTS + (size_t)i * 5;
        bool keep = lbl >= 0;
        #pragma unroll
        for (int c5 = 0; c5 < 5; c5++) o[c5] = keep ? r[c5] : 0.0f;
    }
}

extern "C" void kernel_launch(void* const* d_in, const int* in_sizes, int n_in,
                              void* d_out, int out_size, void* d_ws, size_t ws_size,
                              hipStream_t stream) {
    const float* x = (const float*)d_in[0];
    float* out = (float*)d_out;
    char* ws = (char*)d_ws;

    // workspace (~2.03 MB); NOTHING needs pre-zeroing (plain-stored counts/masks)
    unsigned int* eAll       = (unsigned int*)(ws);                 // 240*2048*4 = 1966080
    int* ecnt                = (int*)(ws + 1966080);                // 240*4 (pad 1024)
    unsigned long long* cbm  = (unsigned long long*)(ws + 1967104); // 240*8 = 1920
    int* nlist_g             = (int*)(ws + 1969024);                // 61440
    int* nn_g                = (int*)(ws + 2030464);                // 64

    k_pairs<<<NGROUPS * NSLICE, PT, 0, stream>>>(x, eAll, ecnt, cbm, nlist_g, nn_g);
    k_graph<<<NGROUPS, GT, 0, stream>>>(eAll, ecnt, cbm, nlist_g, nn_g, x, out);
}